// Round 7
// baseline (263.894 us; speedup 1.0000x reference)
//
#include <hip/hip_runtime.h>

#define NUM_ENT 200000
#define BQ 128
#define DIM 128
#define EN 64      // entity rows per block tile (staged in LDS as f16)
#define QT 64      // queries per block  (gridDim.y = BQ/QT = 2)
#define QW 16      // queries per wave   (4 waves/block)

typedef __fp16 h2 __attribute__((ext_vector_type(2)));   // matches builtin 'V2h'
typedef __attribute__((ext_vector_type(4))) unsigned int uint4v;

static __device__ __forceinline__ unsigned int pkrtz_u(float a, float b) {
    h2 h = __builtin_amdgcn_cvt_pkrtz(a, b);
    return __builtin_bit_cast(unsigned int, h);
}
static __device__ __forceinline__ h2 u_h2(unsigned int u) {
    return __builtin_bit_cast(h2, u);
}
static __device__ __forceinline__ h2 habs2(h2 x) {
    unsigned int u = __builtin_bit_cast(unsigned int, x) & 0x7FFF7FFFu;
    return __builtin_bit_cast(h2, u);
}

#if __has_builtin(__builtin_amdgcn_fdot2)
static __device__ __forceinline__ float fdot2(h2 a, h2 b, float c) {
    return __builtin_amdgcn_fdot2(a, b, c, false);
}
#else
static __device__ __forceinline__ float fdot2(h2 a, h2 b, float c) {
    return c + (float)a[0] * (float)b[0] + (float)a[1] * (float)b[1];
}
#endif

// Kernel 1: q16[b][d/2] = pack_f16(E[h]+R[r]+T[t]) — 128 blocks x 64 threads
__global__ void build_query_kernel(const float* __restrict__ ent,
                                   const float* __restrict__ rel,
                                   const float* __restrict__ tim,
                                   const int* __restrict__ h_idx,
                                   const int* __restrict__ r_idx,
                                   const int* __restrict__ t_idx,
                                   unsigned int* __restrict__ q16) {
    const int b = blockIdx.x, i = threadIdx.x;
    const int d = i * 2;
    const float* eh = ent + (size_t)h_idx[b] * DIM;
    const float* rr = rel + (size_t)r_idx[b] * DIM;
    const float* tt = tim + (size_t)t_idx[b] * DIM;
    float x0 = eh[d] + rr[d] + tt[d];
    float x1 = eh[d + 1] + rr[d + 1] + tt[d + 1];
    q16[b * (DIM / 2) + i] = pkrtz_u(x0, x1);
}

// Kernel 2: block stages 64 entity rows (f32->f16, XOR-swizzled) into 16KB LDS;
// each thread scores 1 entity x 16 queries. Wave index made uniform via
// readfirstlane so q loads scalarize to s_load_dwordx4 (SGPR operands).
__global__ __launch_bounds__(256) void score_kernel(
        const float* __restrict__ ent,
        const unsigned int* __restrict__ q16,
        float* __restrict__ out) {
    __shared__ __align__(16) unsigned int lds[EN * 64];  // 64 rows * 256B (f16)

    const int tid = threadIdx.x;
    const int n0 = blockIdx.x * EN;          // NUM_ENT = 64*3125 exactly
    const int qt = blockIdx.y * QT;

    // ---- stage: 32KB f32 (contiguous rows) -> 16KB f16 LDS, swizzled ----
#pragma unroll
    for (int p = 0; p < 2; ++p) {
        const int tt = tid + p * 256;
        const int r = tt >> 3;        // row 0..63
        const int sub = tt & 7;       // 16-float sub-chunk within row
        const float* gp = ent + (size_t)(n0 + r) * DIM + sub * 16;
        float4 a = *(const float4*)(gp);
        float4 b = *(const float4*)(gp + 4);
        float4 c = *(const float4*)(gp + 8);
        float4 d = *(const float4*)(gp + 12);
        uint4v w0 = { pkrtz_u(a.x, a.y), pkrtz_u(a.z, a.w),
                      pkrtz_u(b.x, b.y), pkrtz_u(b.z, b.w) };
        uint4v w1 = { pkrtz_u(c.x, c.y), pkrtz_u(c.z, c.w),
                      pkrtz_u(d.x, d.y), pkrtz_u(d.z, d.w) };
        const int c16 = sub * 2;      // 16B slot index (0..15)
        const int k = r & 7;          // swizzle key
        *(uint4v*)&lds[r * 64 + ((c16    ) ^ k) * 4] = w0;
        *(uint4v*)&lds[r * 64 + ((c16 + 1) ^ k) * 4] = w1;
    }
    __syncthreads();

    // ---- compute: 1 entity/thread x 16 queries ----
    const int lane = tid & 63;
    const int wv = __builtin_amdgcn_readfirstlane(tid >> 6);   // uniform!
    const uint4v* __restrict__ qv =
        (const uint4v*)q16 + (size_t)(qt + wv * QW) * (DIM / 8);
    const int k = lane & 7;
    const unsigned int* __restrict__ lrow = lds + lane * 64;

    float acc[QW];
#pragma unroll
    for (int tb = 0; tb < QW; ++tb) acc[tb] = 0.0f;

    const h2 one = { (__fp16)1.0f, (__fp16)1.0f };

#pragma unroll
    for (int c16 = 0; c16 < 16; ++c16) {     // 16B f16 slot = 8 dims
        uint4v e = *(const uint4v*)&lrow[(c16 ^ k) * 4];
        h2 e0 = u_h2(e[0]), e1 = u_h2(e[1]), e2 = u_h2(e[2]), e3 = u_h2(e[3]);
#pragma unroll
        for (int g = 0; g < 2; ++g) {        // 2 groups of 8 queries
            uint4v uq[8];
#pragma unroll
            for (int j = 0; j < 8; ++j)
                uq[j] = qv[(size_t)(g * 8 + j) * (DIM / 8) + c16];
#pragma unroll
            for (int j = 0; j < 8; ++j) {
                h2 q0 = u_h2(uq[j][0]), q1 = u_h2(uq[j][1]);
                h2 q2 = u_h2(uq[j][2]), q3 = u_h2(uq[j][3]);
                float a0 = acc[g * 8 + j];
                a0 = fdot2(habs2(q0 - e0), one, a0);
                a0 = fdot2(habs2(q1 - e1), one, a0);
                a0 = fdot2(habs2(q2 - e2), one, a0);
                a0 = fdot2(habs2(q3 - e3), one, a0);
                acc[g * 8 + j] = a0;
            }
        }
    }

    // ---- store: lane -> entity (coalesced dwords) ----
    const int n = n0 + lane;
#pragma unroll
    for (int tb = 0; tb < QW; ++tb)
        out[(size_t)(qt + wv * QW + tb) * NUM_ENT + n] = -acc[tb];
}

extern "C" void kernel_launch(void* const* d_in, const int* in_sizes, int n_in,
                              void* d_out, int out_size, void* d_ws, size_t ws_size,
                              hipStream_t stream) {
    const float* ent = (const float*)d_in[0];
    const float* rel = (const float*)d_in[1];
    const float* tim = (const float*)d_in[2];
    const int*   h_idx = (const int*)d_in[3];
    const int*   r_idx = (const int*)d_in[4];
    const int*   t_idx = (const int*)d_in[5];
    float* out = (float*)d_out;
    unsigned int* q16 = (unsigned int*)d_ws;   // 128 x 64 dwords = 32 KB

    build_query_kernel<<<BQ, 64, 0, stream>>>(ent, rel, tim, h_idx, r_idx, t_idx, q16);

    const int nblocks = NUM_ENT / EN;          // 3125 exact
    dim3 grid(nblocks, BQ / QT);               // (3125, 2)
    score_kernel<<<grid, 256, 0, stream>>>(ent, q16, out);
}

// Round 8
// 132.106 us; speedup vs baseline: 1.9976x; 1.9976x over previous
//
#include <hip/hip_runtime.h>

#define NUM_ENT 200000
#define BQ 128
#define DIM 128
#define EN 64      // entity rows per block tile (f32 in LDS), = lanes/wave
#define QW 8       // queries per wave
#define WAVES 4
#define QT (QW * WAVES)   // 32 queries per block; gridDim.y = BQ/QT = 4

// Kernel 1: query[b][d] = E[h[b]][d] + R[r[b]][d] + T[t[b]][d]  (f32)
__global__ void build_query_kernel(const float* __restrict__ ent,
                                   const float* __restrict__ rel,
                                   const float* __restrict__ tim,
                                   const int* __restrict__ h_idx,
                                   const int* __restrict__ r_idx,
                                   const int* __restrict__ t_idx,
                                   float* __restrict__ q) {
    const int b = blockIdx.x;
    const int d = threadIdx.x;
    q[b * DIM + d] = ent[(size_t)h_idx[b] * DIM + d]
                   + rel[(size_t)r_idx[b] * DIM + d]
                   + tim[(size_t)t_idx[b] * DIM + d];
}

// Kernel 2: block = 64 entities x 32 queries. Entity tile staged f32 in LDS
// (XOR-swizzled 16B slots: slot' = (s&24)|((s^row)&7) -> 8-way bank spread,
// 2 lanes/bank = conflict-free). Thread = 1 entity x 8 queries, pure f32:
// v_sub_f32 + v_add_f32(|mod|) = 2 VALU/element. q loads are wave-uniform
// dwordx4 (SGPR base + imm offset, all within 4KB window) -> L1 broadcast.
__global__ __launch_bounds__(256) void score_kernel(
        const float* __restrict__ ent,
        const float* __restrict__ q,
        float* __restrict__ out) {
    __shared__ __align__(16) float lds[EN * DIM];   // 32 KB

    const int tid = threadIdx.x;
    const int n0 = blockIdx.x * EN;          // NUM_ENT = 64*3125 exactly
    const int qt = blockIdx.y * QT;

    // ---- stage: 64 rows x 512B, fully coalesced, swizzled 16B slots ----
#pragma unroll
    for (int p = 0; p < 8; ++p) {
        const int idx = tid + p * 256;       // 0..2047 16B-slots
        const int row = idx >> 5;            // 32 slots per row
        const int s   = idx & 31;
        const int sw  = (s & 24) | ((s ^ row) & 7);
        const float4 v = *(const float4*)(ent + (size_t)n0 * DIM + (size_t)idx * 4);
        *(float4*)&lds[row * DIM + sw * 4] = v;
    }
    __syncthreads();

    // ---- compute: 1 entity/lane x 8 queries/wave ----
    const int lane = tid & 63;
    const int wv = __builtin_amdgcn_readfirstlane(tid >> 6);   // uniform
    const float* __restrict__ qbase = q + (size_t)(qt + wv * QW) * DIM;
    const int k = lane & 7;
    const float* __restrict__ lrow = lds + lane * DIM;

    // precomputed per-lane swizzle offsets (dwords) for slot low-3 bits
    int xof[8];
#pragma unroll
    for (int j = 0; j < 8; ++j) xof[j] = ((j ^ k) & 7) * 4;

    float acc[QW];
#pragma unroll
    for (int j = 0; j < QW; ++j) acc[j] = 0.0f;

#pragma unroll
    for (int c = 0; c < 32; ++c) {           // 16B slot = 4 dims
        const float4 e = *(const float4*)(lrow + (c & 24) * 4 + xof[c & 7]);
        float4 qv[QW];
#pragma unroll
        for (int j = 0; j < QW; ++j)
            qv[j] = *(const float4*)(qbase + j * DIM + c * 4);
#pragma unroll
        for (int j = 0; j < QW; ++j) {
            float d0 = qv[j].x - e.x;
            float d1 = qv[j].y - e.y;
            float d2 = qv[j].z - e.z;
            float d3 = qv[j].w - e.w;
            acc[j] += fabsf(d0);
            acc[j] += fabsf(d1);
            acc[j] += fabsf(d2);
            acc[j] += fabsf(d3);
        }
    }

    // ---- store: lane -> entity (coalesced dwords) ----
    const int n = n0 + lane;
#pragma unroll
    for (int j = 0; j < QW; ++j)
        out[(size_t)(qt + wv * QW + j) * NUM_ENT + n] = -acc[j];
}

extern "C" void kernel_launch(void* const* d_in, const int* in_sizes, int n_in,
                              void* d_out, int out_size, void* d_ws, size_t ws_size,
                              hipStream_t stream) {
    const float* ent = (const float*)d_in[0];
    const float* rel = (const float*)d_in[1];
    const float* tim = (const float*)d_in[2];
    const int*   h_idx = (const int*)d_in[3];
    const int*   r_idx = (const int*)d_in[4];
    const int*   t_idx = (const int*)d_in[5];
    float* out = (float*)d_out;
    float* qf  = (float*)d_ws;   // 128 x 128 f32 = 64 KB scratch

    build_query_kernel<<<BQ, DIM, 0, stream>>>(ent, rel, tim, h_idx, r_idx, t_idx, qf);

    const int nblocks = NUM_ENT / EN;        // 3125 exact
    dim3 grid(nblocks, BQ / QT);             // (3125, 4)
    score_kernel<<<grid, 256, 0, stream>>>(ent, qf, out);
}